// Round 10
// baseline (261.543 us; speedup 1.0000x reference)
//
#include <hip/hip_runtime.h>
#include <math.h>

#define NT 16384
#define D 4096
#define NE 128
#define KS 1024           // K per wave (block-internal split-K across 4 waves)
#define NCH 32            // chunks per wave (BK=32)
#define BMT 32            // tokens per block
#define INV_T (1.0f / 0.07f)
#define TAU 4e-5f
#define FIXCAP 16384

typedef _Float16 h16;
typedef _Float16 h8 __attribute__((ext_vector_type(8)));
typedef _Float16 h4 __attribute__((ext_vector_type(4)));
typedef float f4 __attribute__((ext_vector_type(4)));
typedef float f16v __attribute__((ext_vector_type(16)));

// ---- static device scratch (fully rewritten each call) ----
__device__ float g_wgn[NE * D];          // normalized W fp32 (fixup)
// W hi-plane packed: [kslice][chunk][kh][g][oct][e32][8 h16] -> 8KB per (slice,chunk)
__device__ __align__(16) h16 g_wpk[NE * D];
__device__ int   g_tte[NT];
__device__ int   g_cnt;
__device__ int   g_flag[FIXCAP];
__device__ float g_cand[FIXCAP][NE];     // cosine logits of flagged tokens
__device__ float g_me[NT / BMT][NE];     // per-block softmax column sums (512 rows)
__device__ int   g_hist[256][NE];        // per-64-token-chunk histograms (atomic)
__device__ int   g_pos[256][NE];

// ---------------- kernel 1: normalize W + fp16 hi split + pack + hist zero ----
__global__ __launch_bounds__(256) void k_prep(const float* __restrict__ wg) {
    int e = blockIdx.x;
    int tid = threadIdx.x;
    if (e == 0 && tid == 0) g_cnt = 0;
    g_hist[e * 2 + (tid >> 7)][tid & 127] = 0;   // 128 blocks x 256 thr = all 256x128
    const f4* row = (const f4*)(wg + (size_t)e * D);
    float ss = 0.f;
    f4 v[4];
    #pragma unroll
    for (int c = 0; c < 4; c++) {
        v[c] = row[tid + 256 * c];
        ss += v[c][0]*v[c][0] + v[c][1]*v[c][1] + v[c][2]*v[c][2] + v[c][3]*v[c][3];
    }
    __shared__ float red[4];
    #pragma unroll
    for (int o = 32; o > 0; o >>= 1) ss += __shfl_xor(ss, o, 64);
    if ((tid & 63) == 0) red[tid >> 6] = ss;
    __syncthreads();
    float den = fmaxf(sqrtf(red[0] + red[1] + red[2] + red[3]), 1e-4f);
    int g = e >> 5, e5 = e & 31;
    #pragma unroll
    for (int cc = 0; cc < 4; cc++) {
        int k0 = (tid + 256 * cc) * 4;
        f4 wn;
        h4 hi;
        #pragma unroll
        for (int k = 0; k < 4; k++) {
            wn[k] = v[cc][k] / den;
            hi[k] = (h16)wn[k];
        }
        *(f4*)(g_wgn + (size_t)e * D + k0) = wn;
        // pack: k -> slice=k>>10, kc=(k>>5)&31, kh=(k>>4)&1, oct=(k>>3)&1, d=k&7
        int slice = k0 >> 10, kc = (k0 >> 5) & 31;
        int kh = (k0 >> 4) & 1, oct = (k0 >> 3) & 1;
        size_t off = (size_t)(slice * 32 + kc) * 8192 + (size_t)kh * 4096
                   + (size_t)g * 1024 + (size_t)oct * 512 + (size_t)e5 * 16
                   + (size_t)(k0 & 7) * 2;
        *(h4*)((char*)g_wpk + off) = hi;
    }
}

// ---------------- kernel 2: fused fp16x2 32x32x16 GEMM + epilogue -------------
// grid 512 (2 blk/CU), 256 thr = 4 waves. Block: 32 tokens x 128 experts x K=4096.
// Wave w owns K-quarter [w*1024, +1024). No barriers/LDS in the K-loop.
// Latency plan: x prefetch 4 chunks deep (~1400cyc > HBM 900), W 2 deep
// (~500cyc > L2 200); setprio(1) around MFMA (free-running waves = T5 regime).
__global__ __launch_bounds__(256, 2) void k_gemm(const float* __restrict__ x) {
    __shared__ float red[2][32][128];    // 32KB: pairwise K-slice reduction + gates
    __shared__ float ssqr[4][32];
    __shared__ int hh[NE];

    const int tid = threadIdx.x;
    const int t0 = blockIdx.x * BMT;
    const int w = tid >> 6, l = tid & 63;
    const int e5 = l & 31, oct = l >> 5;

    const char* wbase = (const char*)g_wpk + (size_t)w * 32 * 8192
                        + (size_t)oct * 512 + (size_t)e5 * 16;
    const float* xb = x + (size_t)(t0 + e5) * D + w * KS + oct * 8;

    if (tid < NE) hh[tid] = 0;

    f16v acc[4];
    acc[0] = (f16v)0.0f; acc[1] = (f16v)0.0f;
    acc[2] = (f16v)0.0f; acc[3] = (f16v)0.0f;
    float ssq = 0.f;
    f4 x0[4], x1[4], x2[4], x3[4];
    h8 ah[2], al[2], b0[8], b1[8], b2[8], b3[8];

#define LOADW(B_, c) do { _Pragma("unroll") for (int j = 0; j < 8; j++) \
        B_[j] = *(const h8*)(wbase + (size_t)(c) * 8192 + (j >> 2) * 4096 + (j & 3) * 1024); } while (0)

#define LOADX(X, c) do { \
        X[0] = *(const f4*)(xb + (c) * 32); \
        X[1] = *(const f4*)(xb + (c) * 32 + 4); \
        X[2] = *(const f4*)(xb + (c) * 32 + 16); \
        X[3] = *(const f4*)(xb + (c) * 32 + 20); } while (0)

#define CONVX(X) do { _Pragma("unroll") for (int q = 0; q < 4; q++) { \
        _Pragma("unroll") for (int e2 = 0; e2 < 4; e2++) { \
            float f_ = X[q][e2]; \
            ssq += f_ * f_; \
            h16 h_ = (h16)f_; \
            ah[q >> 1][(q & 1) * 4 + e2] = h_; \
            al[q >> 1][(q & 1) * 4 + e2] = (h16)(f_ - (float)h_); } } } while (0)

#define MFMAC(B_) do { \
        __builtin_amdgcn_s_setprio(1); \
        _Pragma("unroll") for (int kh = 0; kh < 2; kh++) \
        _Pragma("unroll") for (int g = 0; g < 4; g++) { \
            acc[g] = __builtin_amdgcn_mfma_f32_32x32x16_f16(ah[kh], B_[kh * 4 + g], acc[g], 0, 0, 0); \
            acc[g] = __builtin_amdgcn_mfma_f32_32x32x16_f16(al[kh], B_[kh * 4 + g], acc[g], 0, 0, 0); } \
        __builtin_amdgcn_s_setprio(0); } while (0)

// one sub-step: W loaded 2 chunks ahead, x 4 chunks ahead, then MFMA
#define SUB(C, WLD, WK, XS, XK, WMM) do { \
        if ((C) + (WK) < NCH) LOADW(WLD, (C) + (WK)); \
        CONVX(XS); \
        if ((C) + (XK) < NCH) LOADX(XS, (C) + (XK)); \
        MFMAC(WMM); } while (0)

    LOADW(b0, 0);
    LOADW(b1, 1);
    LOADX(x0, 0);
    LOADX(x1, 1);
    LOADX(x2, 2);
    LOADX(x3, 3);
    #pragma unroll 1
    for (int c = 0; c < NCH; c += 4) {
        SUB(c, b2, 2, x0, 4, b0);
        SUB(c, b3, 3, x1, 5, b1);
        SUB(c, b0, 4, x2, 6, b2);
        SUB(c, b1, 5, x3, 7, b3);
    }

    // per-token |x|^2 for this K-quarter
    ssq += __shfl_xor(ssq, 32, 64);
    if (l < 32) ssqr[w][l] = ssq;

    // deterministic cross-wave (K-slice) reduction via LDS, 2 rounds
#define ACCST(H) do { _Pragma("unroll") for (int g = 0; g < 4; g++) \
        _Pragma("unroll") for (int q = 0; q < 16; q++) \
            red[H][(q & 3) + 8 * (q >> 2) + 4 * oct][g * 32 + e5] = acc[g][q]; } while (0)
#define ACCADD(H) do { _Pragma("unroll") for (int g = 0; g < 4; g++) \
        _Pragma("unroll") for (int q = 0; q < 16; q++) \
            acc[g][q] += red[H][(q & 3) + 8 * (q >> 2) + 4 * oct][g * 32 + e5]; } while (0)

    __syncthreads();
    if (w == 1) ACCST(0);
    if (w == 3) ACCST(1);
    __syncthreads();
    if (w == 0) ACCADD(0);
    if (w == 2) ACCADD(1);
    __syncthreads();
    if (w == 2) ACCST(1);
    __syncthreads();
    if (w == 0) { ACCADD(1); ACCST(0); }   // full raw dots -> red[0]
    __syncthreads();

    // ---- epilogue: 8 threads per token, 16 experts each ----
    const int tl = tid >> 3, g8 = tid & 7, e0 = g8 * 16;
    float n2 = ssqr[0][tl] + ssqr[1][tl] + ssqr[2][tl] + ssqr[3][tl];
    float scl = 1.0f / fmaxf(sqrtf(n2), 1e-4f);
    float v[16];
    #pragma unroll
    for (int k = 0; k < 16; k += 4) *(f4*)&v[k] = *(const f4*)&red[0][tl][e0 + k];

    float m1 = -1e30f, m2 = -1e30f;
    int a1 = e0;
    #pragma unroll
    for (int k = 0; k < 16; k++) {
        float cv = v[k] * scl;
        v[k] = cv;
        if (cv > m1) { m2 = m1; m1 = cv; a1 = e0 + k; }
        else if (cv > m2) m2 = cv;
    }
    #pragma unroll
    for (int o = 1; o < 8; o <<= 1) {
        float m1o = __shfl_xor(m1, o, 64);
        int   a1o = __shfl_xor(a1, o, 64);
        float m2o = __shfl_xor(m2, o, 64);
        m2 = fmaxf(fmaxf(m2, m2o), fminf(m1, m1o));
        if (m1o > m1 || (m1o == m1 && a1o < a1)) { m1 = m1o; a1 = a1o; }
    }
    const int tg = t0 + tl;
    if (g8 == 0) {
        g_tte[tg] = a1;
        atomicAdd(&hh[a1], 1);
    }
    if (m1 - m2 < TAU) {                   // near-tie -> exact recheck later
        int ix = 0;
        if (g8 == 0) ix = atomicAdd(&g_cnt, 1);
        ix = __shfl(ix, l & ~7, 64);
        if (ix < FIXCAP) {
            if (g8 == 0) g_flag[ix] = tg;
            #pragma unroll
            for (int k = 0; k < 16; k += 4) {
                f4 t4;
                t4[0] = v[k]; t4[1] = v[k + 1]; t4[2] = v[k + 2]; t4[3] = v[k + 3];
                *(f4*)&g_cand[ix][e0 + k] = t4;
            }
        }
    }

    // softmax(cos/0.07)
    float ssum = 0.f;
    #pragma unroll
    for (int k = 0; k < 16; k++) {
        float ex = __expf((v[k] - m1) * INV_T);
        v[k] = ex;
        ssum += ex;
    }
    ssum += __shfl_xor(ssum, 1, 64);
    ssum += __shfl_xor(ssum, 2, 64);
    ssum += __shfl_xor(ssum, 4, 64);
    float inv = 1.0f / ssum;
    #pragma unroll
    for (int k = 0; k < 16; k += 4) {
        f4 t4;
        t4[0] = v[k] * inv; t4[1] = v[k + 1] * inv;
        t4[2] = v[k + 2] * inv; t4[3] = v[k + 3] * inv;
        *(f4*)&red[1][tl][e0 + k] = t4;
    }
    __syncthreads();
    if (tid < NE) {
        float s = 0.f;
        #pragma unroll 8
        for (int r = 0; r < 32; r++) s += red[1][r][tid];
        g_me[blockIdx.x][tid] = s;
        atomicAdd(&g_hist[blockIdx.x >> 1][tid], hh[tid]);
    }

#undef LOADW
#undef LOADX
#undef CONVX
#undef MFMAC
#undef SUB
#undef ACCST
#undef ACCADD
}

// ---------------- kernel 3: exact fp32 recheck of near-tie tokens -------------
// Candidates = experts within TAU (cosine units) of approx max (from g_cand);
// exact fp32 dots only for those, ascending + strict > = first-index tie-break.
__global__ __launch_bounds__(64) void k_fix(const float* __restrict__ x) {
    int n = g_cnt;
    if (n > FIXCAP) n = FIXCAP;
    const int l = threadIdx.x;
    for (int i = blockIdx.x; i < n; i += gridDim.x) {
        int t = g_flag[i];
        float c0 = g_cand[i][l], c1 = g_cand[i][l + 64];
        float m = fmaxf(c0, c1);
        #pragma unroll
        for (int o = 1; o < 64; o <<= 1) m = fmaxf(m, __shfl_xor(m, o, 64));
        float thr = m - TAU;
        unsigned long long b0 = __ballot(c0 >= thr);
        unsigned long long b1 = __ballot(c1 >= thr);

        const float* xr = x + (size_t)t * D;
        float bm = -1e30f;
        int ba = 0;
        #pragma unroll 1
        for (int half = 0; half < 2; half++) {
            unsigned long long b = half ? b1 : b0;
            while (b) {
                int e = (__ffsll((long long)b) - 1) + half * 64;
                b &= b - 1;
                const float* wr = g_wgn + (size_t)e * D;
                float s = 0.f;
                #pragma unroll 4
                for (int c = 0; c < 16; c++) {
                    f4 xv = *(const f4*)(xr + c * 256 + l * 4);
                    f4 wv = *(const f4*)(wr + c * 256 + l * 4);
                    s = fmaf(xv[0], wv[0], s);
                    s = fmaf(xv[1], wv[1], s);
                    s = fmaf(xv[2], wv[2], s);
                    s = fmaf(xv[3], wv[3], s);
                }
                #pragma unroll
                for (int o = 1; o < 64; o <<= 1) s += __shfl_xor(s, o, 64);
                if (s > bm) { bm = s; ba = e; }
            }
        }
        if (l == 0) {
            int old = g_tte[t];
            if (ba != old) {
                g_tte[t] = ba;
                atomicSub(&g_hist[t >> 6][old], 1);
                atomicAdd(&g_hist[t >> 6][ba], 1);
            }
        }
    }
}

// ---------------- kernel 4: scans + l_aux + splits ----------------------------
__global__ __launch_bounds__(128) void k_scan(float* __restrict__ out) {
    __shared__ int total[NE];
    __shared__ float me[NE];
    int e = threadIdx.x;
    int run = 0;
    #pragma unroll 8
    for (int c = 0; c < 256; c++) run += g_hist[c][e];
    total[e] = run;
    __syncthreads();
    int off = 0;
    for (int i = 0; i < e; i++) off += total[i];
    int p = off;
    for (int c = 0; c < 256; c++) { g_pos[c][e] = p; p += g_hist[c][e]; }
    float s = 0.f;
    #pragma unroll 8
    for (int b = 0; b < NT / BMT; b++) s += g_me[b][e];
    me[e] = s;
    __syncthreads();
    if (e == 0) {
        float acc = 0.f;
        for (int i = 0; i < NE; i++)
            acc += me[i] * ((float)total[i] * (1.0f / 16384.0f) + 1e-6f);
        out[0] = acc * 128.0f;   // l_aux
    }
    out[1 + NT + e]      = (float)total[e];   // input_splits
    out[1 + NT + NE + e] = (float)total[e];   // output_splits
}

// ---------------- kernel 5: stable placement (counting sort) ------------------
__global__ __launch_bounds__(64) void k_place(float* __restrict__ out) {
    __shared__ int arr[64];
    int tid = threadIdx.x;
    int c = blockIdx.x;
    int t = c * 64 + tid;
    int e = g_tte[t];
    arr[tid] = e;
    __syncthreads();
    int rank = 0;
    for (int j = 0; j < tid; j++) rank += (arr[j] == e) ? 1 : 0;
    out[1 + g_pos[c][e] + rank] = (float)t;
}

// ---------------- launcher ----------------------------------------------------
extern "C" void kernel_launch(void* const* d_in, const int* in_sizes, int n_in,
                              void* d_out, int out_size, void* d_ws, size_t ws_size,
                              hipStream_t stream) {
    const float* x  = (const float*)d_in[0];
    const float* wg = (const float*)d_in[1];
    // d_in[2] = gating_t: sigmoid(x/temp) is monotonic -> argmax unaffected
    float* out = (float*)d_out;

    k_prep<<<NE, 256, 0, stream>>>(wg);
    k_gemm<<<NT / BMT, 256, 0, stream>>>(x);
    k_fix<<<1024, 64, 0, stream>>>(x);
    k_scan<<<1, 128, 0, stream>>>(out);
    k_place<<<256, 64, 0, stream>>>(out);
}

// Round 12
// 145.223 us; speedup vs baseline: 1.8010x; 1.8010x over previous
//
#include <hip/hip_runtime.h>
#include <math.h>

#define NT 16384
#define D 4096
#define NE 128
#define KS 1024           // K per wave (block-internal split-K across 4 waves)
#define NCH 32            // chunks per wave (BK=32)
#define BMT 32            // tokens per block
#define INV_T (1.0f / 0.07f)
#define TAU 4e-5f
#define FIXCAP 16384

typedef _Float16 h16;
typedef _Float16 h8 __attribute__((ext_vector_type(8)));
typedef _Float16 h4 __attribute__((ext_vector_type(4)));
typedef float f4 __attribute__((ext_vector_type(4)));
typedef float f16v __attribute__((ext_vector_type(16)));

// ---- static device scratch (fully rewritten each call) ----
__device__ float g_wgn[NE * D];          // normalized W fp32 (fixup)
// W hi-plane packed: [kslice][chunk][kh][g][oct][e32][8 h16] -> 8KB per (slice,chunk)
__device__ __align__(16) h16 g_wpk[NE * D];
__device__ int   g_tte[NT];
__device__ int   g_cnt;
__device__ int   g_flag[FIXCAP];
__device__ float g_cand[FIXCAP][NE];     // cosine logits of flagged tokens
__device__ float g_me[NT / BMT][NE];     // per-block softmax column sums (512 rows)
__device__ int   g_hist[256][NE];        // per-64-token-chunk histograms (atomic)
__device__ int   g_pos[256][NE];

// ---------------- kernel 1: normalize W + fp16 hi split + pack + hist zero ----
__global__ __launch_bounds__(256) void k_prep(const float* __restrict__ wg) {
    int e = blockIdx.x;
    int tid = threadIdx.x;
    if (e == 0 && tid == 0) g_cnt = 0;
    g_hist[e * 2 + (tid >> 7)][tid & 127] = 0;   // 128 blocks x 256 thr = all 256x128
    const f4* row = (const f4*)(wg + (size_t)e * D);
    float ss = 0.f;
    f4 v[4];
    #pragma unroll
    for (int c = 0; c < 4; c++) {
        v[c] = row[tid + 256 * c];
        ss += v[c][0]*v[c][0] + v[c][1]*v[c][1] + v[c][2]*v[c][2] + v[c][3]*v[c][3];
    }
    __shared__ float red[4];
    #pragma unroll
    for (int o = 32; o > 0; o >>= 1) ss += __shfl_xor(ss, o, 64);
    if ((tid & 63) == 0) red[tid >> 6] = ss;
    __syncthreads();
    float den = fmaxf(sqrtf(red[0] + red[1] + red[2] + red[3]), 1e-4f);
    int g = e >> 5, e5 = e & 31;
    #pragma unroll
    for (int cc = 0; cc < 4; cc++) {
        int k0 = (tid + 256 * cc) * 4;
        f4 wn;
        h4 hi;
        #pragma unroll
        for (int k = 0; k < 4; k++) {
            wn[k] = v[cc][k] / den;
            hi[k] = (h16)wn[k];
        }
        *(f4*)(g_wgn + (size_t)e * D + k0) = wn;
        // pack: k -> slice=k>>10, kc=(k>>5)&31, kh=(k>>4)&1, oct=(k>>3)&1, d=k&7
        int slice = k0 >> 10, kc = (k0 >> 5) & 31;
        int kh = (k0 >> 4) & 1, oct = (k0 >> 3) & 1;
        size_t off = (size_t)(slice * 32 + kc) * 8192 + (size_t)kh * 4096
                   + (size_t)g * 1024 + (size_t)oct * 512 + (size_t)e5 * 16
                   + (size_t)(k0 & 7) * 2;
        *(h4*)((char*)g_wpk + off) = hi;
    }
}

// ---------------- kernel 2: fused fp16x2 32x32x16 GEMM + epilogue -------------
// grid 512 (2 blk/CU), 256 thr = 4 waves. Block: 32 tokens x 128 experts x K=4096.
// Wave w owns K-quarter [w*1024, +1024). No barriers/LDS in the K-loop.
// W ping-pong depth 1 (every sub-step loads chunk C+1 into the buffer just
// consumed -- r9's proven schedule); x prefetch depth 4 (>1000cyc > HBM ~900).
// Register budget ~230 < 256 -> no spill at 2 waves/SIMD.
__global__ __launch_bounds__(256, 2) void k_gemm(const float* __restrict__ x) {
    __shared__ float red[2][32][128];    // 32KB: pairwise K-slice reduction + gates
    __shared__ float ssqr[4][32];
    __shared__ int hh[NE];

    const int tid = threadIdx.x;
    const int t0 = blockIdx.x * BMT;
    const int w = tid >> 6, l = tid & 63;
    const int e5 = l & 31, oct = l >> 5;

    const char* wbase = (const char*)g_wpk + (size_t)w * 32 * 8192
                        + (size_t)oct * 512 + (size_t)e5 * 16;
    const float* xb = x + (size_t)(t0 + e5) * D + w * KS + oct * 8;

    if (tid < NE) hh[tid] = 0;

    f16v acc[4];
    acc[0] = (f16v)0.0f; acc[1] = (f16v)0.0f;
    acc[2] = (f16v)0.0f; acc[3] = (f16v)0.0f;
    float sq0 = 0.f, sq1 = 0.f, sq2 = 0.f, sq3 = 0.f;
    f4 x0[4], x1[4], x2[4], x3[4];
    h8 ah[2], al[2], bA[8], bB[8];

#define LOADW(B_, c) do { _Pragma("unroll") for (int j = 0; j < 8; j++) \
        B_[j] = *(const h8*)(wbase + (size_t)(c) * 8192 + (j >> 2) * 4096 + (j & 3) * 1024); } while (0)

#define LOADX(X, c) do { \
        X[0] = *(const f4*)(xb + (c) * 32); \
        X[1] = *(const f4*)(xb + (c) * 32 + 4); \
        X[2] = *(const f4*)(xb + (c) * 32 + 16); \
        X[3] = *(const f4*)(xb + (c) * 32 + 20); } while (0)

#define CONVX(X) do { \
        _Pragma("unroll") for (int e2 = 0; e2 < 4; e2++) { \
            float f0_ = X[0][e2], f1_ = X[1][e2], f2_ = X[2][e2], f3_ = X[3][e2]; \
            sq0 = fmaf(f0_, f0_, sq0); sq1 = fmaf(f1_, f1_, sq1); \
            sq2 = fmaf(f2_, f2_, sq2); sq3 = fmaf(f3_, f3_, sq3); \
            h16 h0_ = (h16)f0_, h1_ = (h16)f1_, h2_ = (h16)f2_, h3_ = (h16)f3_; \
            ah[0][e2] = h0_;     ah[0][e2 + 4] = h1_; \
            ah[1][e2] = h2_;     ah[1][e2 + 4] = h3_; \
            al[0][e2] = (h16)(f0_ - (float)h0_); al[0][e2 + 4] = (h16)(f1_ - (float)h1_); \
            al[1][e2] = (h16)(f2_ - (float)h2_); al[1][e2 + 4] = (h16)(f3_ - (float)h3_); } } while (0)

#define MFMAC(B_) do { \
        __builtin_amdgcn_s_setprio(1); \
        _Pragma("unroll") for (int kh = 0; kh < 2; kh++) \
        _Pragma("unroll") for (int g = 0; g < 4; g++) { \
            acc[g] = __builtin_amdgcn_mfma_f32_32x32x16_f16(ah[kh], B_[kh * 4 + g], acc[g], 0, 0, 0); \
            acc[g] = __builtin_amdgcn_mfma_f32_32x32x16_f16(al[kh], B_[kh * 4 + g], acc[g], 0, 0, 0); } \
        __builtin_amdgcn_s_setprio(0); } while (0)

// one sub-step at chunk C: load next W chunk (C+1) into the buffer just
// consumed last step (WLD), convert+consume x-chunk XS, refill XS 4 ahead,
// multiply with WMM (holds chunk C).
#define SUB(C, WLD, XS, WMM) do { \
        if ((C) + 1 < NCH) LOADW(WLD, (C) + 1); \
        CONVX(XS); \
        if ((C) + 4 < NCH) LOADX(XS, (C) + 4); \
        MFMAC(WMM); } while (0)

    LOADW(bA, 0);
    LOADX(x0, 0);
    LOADX(x1, 1);
    LOADX(x2, 2);
    LOADX(x3, 3);
    #pragma unroll 1
    for (int c = 0; c < NCH; c += 4) {
        SUB(c + 0, bB, x0, bA);   // load W(c+1)->bB, mma W(c)  =bA
        SUB(c + 1, bA, x1, bB);   // load W(c+2)->bA, mma W(c+1)=bB
        SUB(c + 2, bB, x2, bA);   // load W(c+3)->bB, mma W(c+2)=bA
        SUB(c + 3, bA, x3, bB);   // load W(c+4)->bA, mma W(c+3)=bB
    }

    // per-token |x|^2 for this K-quarter
    float ssq = (sq0 + sq1) + (sq2 + sq3);
    ssq += __shfl_xor(ssq, 32, 64);
    if (l < 32) ssqr[w][l] = ssq;

    // deterministic cross-wave (K-slice) reduction via LDS, 2 rounds
#define ACCST(H) do { _Pragma("unroll") for (int g = 0; g < 4; g++) \
        _Pragma("unroll") for (int q = 0; q < 16; q++) \
            red[H][(q & 3) + 8 * (q >> 2) + 4 * oct][g * 32 + e5] = acc[g][q]; } while (0)
#define ACCADD(H) do { _Pragma("unroll") for (int g = 0; g < 4; g++) \
        _Pragma("unroll") for (int q = 0; q < 16; q++) \
            acc[g][q] += red[H][(q & 3) + 8 * (q >> 2) + 4 * oct][g * 32 + e5]; } while (0)

    __syncthreads();
    if (w == 1) ACCST(0);
    if (w == 3) ACCST(1);
    __syncthreads();
    if (w == 0) ACCADD(0);
    if (w == 2) ACCADD(1);
    __syncthreads();
    if (w == 2) ACCST(1);
    __syncthreads();
    if (w == 0) { ACCADD(1); ACCST(0); }   // full raw dots -> red[0]
    __syncthreads();

    // ---- epilogue: 8 threads per token, 16 experts each ----
    const int tl = tid >> 3, g8 = tid & 7, e0 = g8 * 16;
    float n2 = ssqr[0][tl] + ssqr[1][tl] + ssqr[2][tl] + ssqr[3][tl];
    float scl = 1.0f / fmaxf(sqrtf(n2), 1e-4f);
    float v[16];
    #pragma unroll
    for (int k = 0; k < 16; k += 4) *(f4*)&v[k] = *(const f4*)&red[0][tl][e0 + k];

    float m1 = -1e30f, m2 = -1e30f;
    int a1 = e0;
    #pragma unroll
    for (int k = 0; k < 16; k++) {
        float cv = v[k] * scl;
        v[k] = cv;
        if (cv > m1) { m2 = m1; m1 = cv; a1 = e0 + k; }
        else if (cv > m2) m2 = cv;
    }
    #pragma unroll
    for (int o = 1; o < 8; o <<= 1) {
        float m1o = __shfl_xor(m1, o, 64);
        int   a1o = __shfl_xor(a1, o, 64);
        float m2o = __shfl_xor(m2, o, 64);
        m2 = fmaxf(fmaxf(m2, m2o), fminf(m1, m1o));
        if (m1o > m1 || (m1o == m1 && a1o < a1)) { m1 = m1o; a1 = a1o; }
    }
    const int tg = t0 + tl;
    if (g8 == 0) {
        g_tte[tg] = a1;
        atomicAdd(&hh[a1], 1);
    }
    if (m1 - m2 < TAU) {                   // near-tie -> exact recheck later
        int ix = 0;
        if (g8 == 0) ix = atomicAdd(&g_cnt, 1);
        ix = __shfl(ix, l & ~7, 64);
        if (ix < FIXCAP) {
            if (g8 == 0) g_flag[ix] = tg;
            #pragma unroll
            for (int k = 0; k < 16; k += 4) {
                f4 t4;
                t4[0] = v[k]; t4[1] = v[k + 1]; t4[2] = v[k + 2]; t4[3] = v[k + 3];
                *(f4*)&g_cand[ix][e0 + k] = t4;
            }
        }
    }

    // softmax(cos/0.07)
    float ssum = 0.f;
    #pragma unroll
    for (int k = 0; k < 16; k++) {
        float ex = __expf((v[k] - m1) * INV_T);
        v[k] = ex;
        ssum += ex;
    }
    ssum += __shfl_xor(ssum, 1, 64);
    ssum += __shfl_xor(ssum, 2, 64);
    ssum += __shfl_xor(ssum, 4, 64);
    float inv = 1.0f / ssum;
    #pragma unroll
    for (int k = 0; k < 16; k += 4) {
        f4 t4;
        t4[0] = v[k] * inv; t4[1] = v[k + 1] * inv;
        t4[2] = v[k + 2] * inv; t4[3] = v[k + 3] * inv;
        *(f4*)&red[1][tl][e0 + k] = t4;
    }
    __syncthreads();
    if (tid < NE) {
        float s = 0.f;
        #pragma unroll 8
        for (int r = 0; r < 32; r++) s += red[1][r][tid];
        g_me[blockIdx.x][tid] = s;
        atomicAdd(&g_hist[blockIdx.x >> 1][tid], hh[tid]);
    }

#undef LOADW
#undef LOADX
#undef CONVX
#undef MFMAC
#undef SUB
#undef ACCST
#undef ACCADD
}

// ---------------- kernel 3: exact fp32 recheck of near-tie tokens -------------
// Candidates = experts within TAU (cosine units) of approx max (from g_cand);
// exact fp32 dots only for those, ascending + strict > = first-index tie-break.
__global__ __launch_bounds__(64) void k_fix(const float* __restrict__ x) {
    int n = g_cnt;
    if (n > FIXCAP) n = FIXCAP;
    const int l = threadIdx.x;
    for (int i = blockIdx.x; i < n; i += gridDim.x) {
        int t = g_flag[i];
        float c0 = g_cand[i][l], c1 = g_cand[i][l + 64];
        float m = fmaxf(c0, c1);
        #pragma unroll
        for (int o = 1; o < 64; o <<= 1) m = fmaxf(m, __shfl_xor(m, o, 64));
        float thr = m - TAU;
        unsigned long long b0 = __ballot(c0 >= thr);
        unsigned long long b1 = __ballot(c1 >= thr);

        const float* xr = x + (size_t)t * D;
        float bm = -1e30f;
        int ba = 0;
        #pragma unroll 1
        for (int half = 0; half < 2; half++) {
            unsigned long long b = half ? b1 : b0;
            while (b) {
                int e = (__ffsll((long long)b) - 1) + half * 64;
                b &= b - 1;
                const float* wr = g_wgn + (size_t)e * D;
                float s = 0.f;
                #pragma unroll 4
                for (int c = 0; c < 16; c++) {
                    f4 xv = *(const f4*)(xr + c * 256 + l * 4);
                    f4 wv = *(const f4*)(wr + c * 256 + l * 4);
                    s = fmaf(xv[0], wv[0], s);
                    s = fmaf(xv[1], wv[1], s);
                    s = fmaf(xv[2], wv[2], s);
                    s = fmaf(xv[3], wv[3], s);
                }
                #pragma unroll
                for (int o = 1; o < 64; o <<= 1) s += __shfl_xor(s, o, 64);
                if (s > bm) { bm = s; ba = e; }
            }
        }
        if (l == 0) {
            int old = g_tte[t];
            if (ba != old) {
                g_tte[t] = ba;
                atomicSub(&g_hist[t >> 6][old], 1);
                atomicAdd(&g_hist[t >> 6][ba], 1);
            }
        }
    }
}

// ---------------- kernel 4: scans + l_aux + splits ----------------------------
__global__ __launch_bounds__(128) void k_scan(float* __restrict__ out) {
    __shared__ int total[NE];
    __shared__ float me[NE];
    int e = threadIdx.x;
    int run = 0;
    #pragma unroll 8
    for (int c = 0; c < 256; c++) run += g_hist[c][e];
    total[e] = run;
    __syncthreads();
    int off = 0;
    for (int i = 0; i < e; i++) off += total[i];
    int p = off;
    for (int c = 0; c < 256; c++) { g_pos[c][e] = p; p += g_hist[c][e]; }
    float s = 0.f;
    #pragma unroll 8
    for (int b = 0; b < NT / BMT; b++) s += g_me[b][e];
    me[e] = s;
    __syncthreads();
    if (e == 0) {
        float acc = 0.f;
        for (int i = 0; i < NE; i++)
            acc += me[i] * ((float)total[i] * (1.0f / 16384.0f) + 1e-6f);
        out[0] = acc * 128.0f;   // l_aux
    }
    out[1 + NT + e]      = (float)total[e];   // input_splits
    out[1 + NT + NE + e] = (float)total[e];   // output_splits
}

// ---------------- kernel 5: stable placement (counting sort) ------------------
__global__ __launch_bounds__(64) void k_place(float* __restrict__ out) {
    __shared__ int arr[64];
    int tid = threadIdx.x;
    int c = blockIdx.x;
    int t = c * 64 + tid;
    int e = g_tte[t];
    arr[tid] = e;
    __syncthreads();
    int rank = 0;
    for (int j = 0; j < tid; j++) rank += (arr[j] == e) ? 1 : 0;
    out[1 + g_pos[c][e] + rank] = (float)t;
}

// ---------------- launcher ----------------------------------------------------
extern "C" void kernel_launch(void* const* d_in, const int* in_sizes, int n_in,
                              void* d_out, int out_size, void* d_ws, size_t ws_size,
                              hipStream_t stream) {
    const float* x  = (const float*)d_in[0];
    const float* wg = (const float*)d_in[1];
    // d_in[2] = gating_t: sigmoid(x/temp) is monotonic -> argmax unaffected
    float* out = (float*)d_out;

    k_prep<<<NE, 256, 0, stream>>>(wg);
    k_gemm<<<NT / BMT, 256, 0, stream>>>(x);
    k_fix<<<1024, 64, 0, stream>>>(x);
    k_scan<<<1, 128, 0, stream>>>(out);
    k_place<<<256, 64, 0, stream>>>(out);
}

// Round 13
// 141.319 us; speedup vs baseline: 1.8507x; 1.0276x over previous
//
#include <hip/hip_runtime.h>
#include <math.h>

#define NT 16384
#define D 4096
#define NE 128
#define KS 1024           // K per wave (block-internal split-K across 4 waves)
#define NCH 32            // chunks per wave (BK=32)
#define BMT 32            // tokens per block
#define INV_T (1.0f / 0.07f)
#define TAU 4e-5f
#define FIXCAP 16384

typedef _Float16 h16;
typedef _Float16 h8 __attribute__((ext_vector_type(8)));
typedef _Float16 h4 __attribute__((ext_vector_type(4)));
typedef float f4 __attribute__((ext_vector_type(4)));
typedef float f16v __attribute__((ext_vector_type(16)));

// ---- static device scratch (fully rewritten each call) ----
__device__ float g_wgn[NE * D];          // normalized W fp32 (fixup)
// W hi-plane packed: [kslice][chunk][kh][g][oct][e32][8 h16] -> 8KB per (slice,chunk)
__device__ __align__(16) h16 g_wpk[NE * D];
__device__ int   g_tte[NT];
__device__ int   g_cnt;
__device__ int   g_flag[FIXCAP];
__device__ float g_cand[FIXCAP][NE];     // cosine logits of flagged tokens
__device__ float g_me[NT / BMT][NE];     // per-block softmax column sums (512 rows)
__device__ int   g_hist[256][NE];        // per-64-token-chunk histograms (atomic)
__device__ int   g_pos[256][NE];

// ---------------- kernel 1: normalize W + fp16 hi split + pack + hist zero ----
__global__ __launch_bounds__(256) void k_prep(const float* __restrict__ wg) {
    int e = blockIdx.x;
    int tid = threadIdx.x;
    if (e == 0 && tid == 0) g_cnt = 0;
    g_hist[e * 2 + (tid >> 7)][tid & 127] = 0;   // 128 blocks x 256 thr = all 256x128
    const f4* row = (const f4*)(wg + (size_t)e * D);
    float ss = 0.f;
    f4 v[4];
    #pragma unroll
    for (int c = 0; c < 4; c++) {
        v[c] = row[tid + 256 * c];
        ss += v[c][0]*v[c][0] + v[c][1]*v[c][1] + v[c][2]*v[c][2] + v[c][3]*v[c][3];
    }
    __shared__ float red[4];
    #pragma unroll
    for (int o = 32; o > 0; o >>= 1) ss += __shfl_xor(ss, o, 64);
    if ((tid & 63) == 0) red[tid >> 6] = ss;
    __syncthreads();
    float den = fmaxf(sqrtf(red[0] + red[1] + red[2] + red[3]), 1e-4f);
    int g = e >> 5, e5 = e & 31;
    #pragma unroll
    for (int cc = 0; cc < 4; cc++) {
        int k0 = (tid + 256 * cc) * 4;
        f4 wn;
        h4 hi;
        #pragma unroll
        for (int k = 0; k < 4; k++) {
            wn[k] = v[cc][k] / den;
            hi[k] = (h16)wn[k];
        }
        *(f4*)(g_wgn + (size_t)e * D + k0) = wn;
        // pack: k -> slice=k>>10, kc=(k>>5)&31, kh=(k>>4)&1, oct=(k>>3)&1, d=k&7
        int slice = k0 >> 10, kc = (k0 >> 5) & 31;
        int kh = (k0 >> 4) & 1, oct = (k0 >> 3) & 1;
        size_t off = (size_t)(slice * 32 + kc) * 8192 + (size_t)kh * 4096
                   + (size_t)g * 1024 + (size_t)oct * 512 + (size_t)e5 * 16
                   + (size_t)(k0 & 7) * 2;
        *(h4*)((char*)g_wpk + off) = hi;
    }
}

// ---------------- kernel 2: fused fp16x2 32x32x16 GEMM + epilogue -------------
// grid 512 (2 blk/CU), 256 thr = 4 waves. Block: 32 tokens x 128 experts x K=4096.
// Wave w owns K-quarter [w*1024, +1024). No barriers/LDS in the K-loop.
// x refills issued as a CLUSTERED 4-chunk burst (512 B contiguous per row in
// one issue window) -> DRAM page locality; W ping-pong depth 1 (L2-resident).
// Register budget ~230 < 256 -> no spill at 2 waves/SIMD. No setprio (m190).
__global__ __launch_bounds__(256, 2) void k_gemm(const float* __restrict__ x) {
    __shared__ float red[2][32][128];    // 32KB: pairwise K-slice reduction + gates
    __shared__ float ssqr[4][32];
    __shared__ int hh[NE];

    const int tid = threadIdx.x;
    const int t0 = blockIdx.x * BMT;
    const int w = tid >> 6, l = tid & 63;
    const int e5 = l & 31, oct = l >> 5;

    const char* wbase = (const char*)g_wpk + (size_t)w * 32 * 8192
                        + (size_t)oct * 512 + (size_t)e5 * 16;
    const float* xb = x + (size_t)(t0 + e5) * D + w * KS + oct * 8;

    if (tid < NE) hh[tid] = 0;

    f16v acc[4];
    acc[0] = (f16v)0.0f; acc[1] = (f16v)0.0f;
    acc[2] = (f16v)0.0f; acc[3] = (f16v)0.0f;
    float sq0 = 0.f, sq1 = 0.f, sq2 = 0.f, sq3 = 0.f;
    f4 x0[4], x1[4], x2[4], x3[4];
    h8 ah[2], al[2], bA[8], bB[8];

#define LOADW(B_, c) do { _Pragma("unroll") for (int j = 0; j < 8; j++) \
        B_[j] = *(const h8*)(wbase + (size_t)(c) * 8192 + (j >> 2) * 4096 + (j & 3) * 1024); } while (0)

#define LOADX(X, c) do { \
        X[0] = *(const f4*)(xb + (c) * 32); \
        X[1] = *(const f4*)(xb + (c) * 32 + 4); \
        X[2] = *(const f4*)(xb + (c) * 32 + 16); \
        X[3] = *(const f4*)(xb + (c) * 32 + 20); } while (0)

#define CONVX(X) do { \
        _Pragma("unroll") for (int e2 = 0; e2 < 4; e2++) { \
            float f0_ = X[0][e2], f1_ = X[1][e2], f2_ = X[2][e2], f3_ = X[3][e2]; \
            sq0 = fmaf(f0_, f0_, sq0); sq1 = fmaf(f1_, f1_, sq1); \
            sq2 = fmaf(f2_, f2_, sq2); sq3 = fmaf(f3_, f3_, sq3); \
            h16 h0_ = (h16)f0_, h1_ = (h16)f1_, h2_ = (h16)f2_, h3_ = (h16)f3_; \
            ah[0][e2] = h0_;     ah[0][e2 + 4] = h1_; \
            ah[1][e2] = h2_;     ah[1][e2 + 4] = h3_; \
            al[0][e2] = (h16)(f0_ - (float)h0_); al[0][e2 + 4] = (h16)(f1_ - (float)h1_); \
            al[1][e2] = (h16)(f2_ - (float)h2_); al[1][e2 + 4] = (h16)(f3_ - (float)h3_); } } while (0)

#define MFMAC(B_) do { \
        _Pragma("unroll") for (int kh = 0; kh < 2; kh++) \
        _Pragma("unroll") for (int g = 0; g < 4; g++) { \
            acc[g] = __builtin_amdgcn_mfma_f32_32x32x16_f16(ah[kh], B_[kh * 4 + g], acc[g], 0, 0, 0); \
            acc[g] = __builtin_amdgcn_mfma_f32_32x32x16_f16(al[kh], B_[kh * 4 + g], acc[g], 0, 0, 0); } } while (0)

    // prologue: W(0), then x batch 0 (chunks 0-3) as one clustered burst
    LOADW(bA, 0);
    LOADX(x0, 0);
    LOADX(x1, 1);
    LOADX(x2, 2);
    LOADX(x3, 3);
    #pragma unroll 1
    for (int c = 0; c < NCH; c += 4) {
        // sub 0: consume x0 + W(c)=bA; load W(c+1)->bB
        if (c + 1 < NCH) LOADW(bB, c + 1);
        CONVX(x0);
        MFMAC(bA);
        // sub 1: consume x1 + W(c+1)=bB; load W(c+2)->bA
        if (c + 2 < NCH) LOADW(bA, c + 2);
        CONVX(x1);
        MFMAC(bB);
        // sub 2: consume x2 + W(c+2)=bA; load W(c+3)->bB
        if (c + 3 < NCH) LOADW(bB, c + 3);
        CONVX(x2);
        MFMAC(bA);
        // sub 3: consume x3 + W(c+3)=bB; load W(c+4)->bA;
        //        issue next x batch as ONE burst (512 B contiguous per row)
        if (c + 4 < NCH) LOADW(bA, c + 4);
        CONVX(x3);
        if (c + 4 < NCH) {
            LOADX(x0, c + 4);
            LOADX(x1, c + 5);
            LOADX(x2, c + 6);
            LOADX(x3, c + 7);
        }
        MFMAC(bB);
    }

    // per-token |x|^2 for this K-quarter
    float ssq = (sq0 + sq1) + (sq2 + sq3);
    ssq += __shfl_xor(ssq, 32, 64);
    if (l < 32) ssqr[w][l] = ssq;

    // deterministic cross-wave (K-slice) reduction via LDS, 2 rounds
#define ACCST(H) do { _Pragma("unroll") for (int g = 0; g < 4; g++) \
        _Pragma("unroll") for (int q = 0; q < 16; q++) \
            red[H][(q & 3) + 8 * (q >> 2) + 4 * oct][g * 32 + e5] = acc[g][q]; } while (0)
#define ACCADD(H) do { _Pragma("unroll") for (int g = 0; g < 4; g++) \
        _Pragma("unroll") for (int q = 0; q < 16; q++) \
            acc[g][q] += red[H][(q & 3) + 8 * (q >> 2) + 4 * oct][g * 32 + e5]; } while (0)

    __syncthreads();
    if (w == 1) ACCST(0);
    if (w == 3) ACCST(1);
    __syncthreads();
    if (w == 0) ACCADD(0);
    if (w == 2) ACCADD(1);
    __syncthreads();
    if (w == 2) ACCST(1);
    __syncthreads();
    if (w == 0) { ACCADD(1); ACCST(0); }   // full raw dots -> red[0]
    __syncthreads();

    // ---- epilogue: 8 threads per token, 16 experts each ----
    const int tl = tid >> 3, g8 = tid & 7, e0 = g8 * 16;
    float n2 = ssqr[0][tl] + ssqr[1][tl] + ssqr[2][tl] + ssqr[3][tl];
    float scl = 1.0f / fmaxf(sqrtf(n2), 1e-4f);
    float v[16];
    #pragma unroll
    for (int k = 0; k < 16; k += 4) *(f4*)&v[k] = *(const f4*)&red[0][tl][e0 + k];

    float m1 = -1e30f, m2 = -1e30f;
    int a1 = e0;
    #pragma unroll
    for (int k = 0; k < 16; k++) {
        float cv = v[k] * scl;
        v[k] = cv;
        if (cv > m1) { m2 = m1; m1 = cv; a1 = e0 + k; }
        else if (cv > m2) m2 = cv;
    }
    #pragma unroll
    for (int o = 1; o < 8; o <<= 1) {
        float m1o = __shfl_xor(m1, o, 64);
        int   a1o = __shfl_xor(a1, o, 64);
        float m2o = __shfl_xor(m2, o, 64);
        m2 = fmaxf(fmaxf(m2, m2o), fminf(m1, m1o));
        if (m1o > m1 || (m1o == m1 && a1o < a1)) { m1 = m1o; a1 = a1o; }
    }
    const int tg = t0 + tl;
    if (g8 == 0) {
        g_tte[tg] = a1;
        atomicAdd(&hh[a1], 1);
    }
    if (m1 - m2 < TAU) {                   // near-tie -> exact recheck later
        int ix = 0;
        if (g8 == 0) ix = atomicAdd(&g_cnt, 1);
        ix = __shfl(ix, l & ~7, 64);
        if (ix < FIXCAP) {
            if (g8 == 0) g_flag[ix] = tg;
            #pragma unroll
            for (int k = 0; k < 16; k += 4) {
                f4 t4;
                t4[0] = v[k]; t4[1] = v[k + 1]; t4[2] = v[k + 2]; t4[3] = v[k + 3];
                *(f4*)&g_cand[ix][e0 + k] = t4;
            }
        }
    }

    // softmax(cos/0.07)
    float ssum = 0.f;
    #pragma unroll
    for (int k = 0; k < 16; k++) {
        float ex = __expf((v[k] - m1) * INV_T);
        v[k] = ex;
        ssum += ex;
    }
    ssum += __shfl_xor(ssum, 1, 64);
    ssum += __shfl_xor(ssum, 2, 64);
    ssum += __shfl_xor(ssum, 4, 64);
    float inv = 1.0f / ssum;
    #pragma unroll
    for (int k = 0; k < 16; k += 4) {
        f4 t4;
        t4[0] = v[k] * inv; t4[1] = v[k + 1] * inv;
        t4[2] = v[k + 2] * inv; t4[3] = v[k + 3] * inv;
        *(f4*)&red[1][tl][e0 + k] = t4;
    }
    __syncthreads();
    if (tid < NE) {
        float s = 0.f;
        #pragma unroll 8
        for (int r = 0; r < 32; r++) s += red[1][r][tid];
        g_me[blockIdx.x][tid] = s;
        atomicAdd(&g_hist[blockIdx.x >> 1][tid], hh[tid]);
    }

#undef LOADW
#undef LOADX
#undef CONVX
#undef MFMAC
#undef ACCST
#undef ACCADD
}

// ---------------- kernel 3: exact fp32 recheck of near-tie tokens -------------
// Candidates = experts within TAU (cosine units) of approx max (from g_cand);
// exact fp32 dots only for those, ascending + strict > = first-index tie-break.
__global__ __launch_bounds__(64) void k_fix(const float* __restrict__ x) {
    int n = g_cnt;
    if (n > FIXCAP) n = FIXCAP;
    const int l = threadIdx.x;
    for (int i = blockIdx.x; i < n; i += gridDim.x) {
        int t = g_flag[i];
        float c0 = g_cand[i][l], c1 = g_cand[i][l + 64];
        float m = fmaxf(c0, c1);
        #pragma unroll
        for (int o = 1; o < 64; o <<= 1) m = fmaxf(m, __shfl_xor(m, o, 64));
        float thr = m - TAU;
        unsigned long long b0 = __ballot(c0 >= thr);
        unsigned long long b1 = __ballot(c1 >= thr);

        const float* xr = x + (size_t)t * D;
        float bm = -1e30f;
        int ba = 0;
        #pragma unroll 1
        for (int half = 0; half < 2; half++) {
            unsigned long long b = half ? b1 : b0;
            while (b) {
                int e = (__ffsll((long long)b) - 1) + half * 64;
                b &= b - 1;
                const float* wr = g_wgn + (size_t)e * D;
                float s = 0.f;
                #pragma unroll 4
                for (int c = 0; c < 16; c++) {
                    f4 xv = *(const f4*)(xr + c * 256 + l * 4);
                    f4 wv = *(const f4*)(wr + c * 256 + l * 4);
                    s = fmaf(xv[0], wv[0], s);
                    s = fmaf(xv[1], wv[1], s);
                    s = fmaf(xv[2], wv[2], s);
                    s = fmaf(xv[3], wv[3], s);
                }
                #pragma unroll
                for (int o = 1; o < 64; o <<= 1) s += __shfl_xor(s, o, 64);
                if (s > bm) { bm = s; ba = e; }
            }
        }
        if (l == 0) {
            int old = g_tte[t];
            if (ba != old) {
                g_tte[t] = ba;
                atomicSub(&g_hist[t >> 6][old], 1);
                atomicAdd(&g_hist[t >> 6][ba], 1);
            }
        }
    }
}

// ---------------- kernel 4: scans + l_aux + splits ----------------------------
__global__ __launch_bounds__(128) void k_scan(float* __restrict__ out) {
    __shared__ int total[NE];
    __shared__ float me[NE];
    int e = threadIdx.x;
    int run = 0;
    #pragma unroll 8
    for (int c = 0; c < 256; c++) run += g_hist[c][e];
    total[e] = run;
    __syncthreads();
    int off = 0;
    for (int i = 0; i < e; i++) off += total[i];
    int p = off;
    for (int c = 0; c < 256; c++) { g_pos[c][e] = p; p += g_hist[c][e]; }
    float s = 0.f;
    #pragma unroll 8
    for (int b = 0; b < NT / BMT; b++) s += g_me[b][e];
    me[e] = s;
    __syncthreads();
    if (e == 0) {
        float acc = 0.f;
        for (int i = 0; i < NE; i++)
            acc += me[i] * ((float)total[i] * (1.0f / 16384.0f) + 1e-6f);
        out[0] = acc * 128.0f;   // l_aux
    }
    out[1 + NT + e]      = (float)total[e];   // input_splits
    out[1 + NT + NE + e] = (float)total[e];   // output_splits
}

// ---------------- kernel 5: stable placement (counting sort) ------------------
__global__ __launch_bounds__(64) void k_place(float* __restrict__ out) {
    __shared__ int arr[64];
    int tid = threadIdx.x;
    int c = blockIdx.x;
    int t = c * 64 + tid;
    int e = g_tte[t];
    arr[tid] = e;
    __syncthreads();
    int rank = 0;
    for (int j = 0; j < tid; j++) rank += (arr[j] == e) ? 1 : 0;
    out[1 + g_pos[c][e] + rank] = (float)t;
}

// ---------------- launcher ----------------------------------------------------
extern "C" void kernel_launch(void* const* d_in, const int* in_sizes, int n_in,
                              void* d_out, int out_size, void* d_ws, size_t ws_size,
                              hipStream_t stream) {
    const float* x  = (const float*)d_in[0];
    const float* wg = (const float*)d_in[1];
    // d_in[2] = gating_t: sigmoid(x/temp) is monotonic -> argmax unaffected
    float* out = (float*)d_out;

    k_prep<<<NE, 256, 0, stream>>>(wg);
    k_gemm<<<NT / BMT, 256, 0, stream>>>(x);
    k_fix<<<1024, 64, 0, stream>>>(x);
    k_scan<<<1, 128, 0, stream>>>(out);
    k_place<<<256, 64, 0, stream>>>(out);
}